// Round 1
// baseline (226.084 us; speedup 1.0000x reference)
//
#include <hip/hip_runtime.h>

#define HH 128
#define WW 128
#define NPIX (HH * WW)        // 16384
#define NC 32                 // in channels
#define NO 32                 // out channels
#define KS 9
#define TAPS 81
#define DIL 2
#define PAD 8
#define OG 4                  // output groups (blockIdx.y)
#define OPG 8                 // outputs per thread
#define CHUNK 27              // taps per LDS staging chunk
#define NCHUNK 3
#define KMIN 1e-6f            // skip threshold; bound: 80*1e-6*0.5 = 4e-5 << 8.8e-4

// ---------------------------------------------------------------------------
// Kernel 1: guidance kernel  k[tap, pix] = exp(-0.5 * sum_c (f[c,q]-f[c,p])^2)
// One thread per (tap, pixel); consecutive lanes = consecutive pixels (coalesced).
// ---------------------------------------------------------------------------
__global__ __launch_bounds__(256) void compute_k_kernel(
    const float* __restrict__ f, float* __restrict__ kbuf)
{
    int tid = blockIdx.x * 256 + threadIdx.x;     // TAPS*NPIX threads exactly
    int pix = tid & (NPIX - 1);
    int tap = tid >> 14;
    int h = pix >> 7, w = pix & (WW - 1);
    int qh = h + (tap / KS) * DIL - PAD;
    int qw = w + (tap % KS) * DIL - PAD;
    bool valid = ((unsigned)qh < HH) & ((unsigned)qw < WW);
    int q = qh * WW + qw;
    float s = 0.f;
#pragma unroll
    for (int c = 0; c < NC; ++c) {
        float fc = f[c * NPIX + pix];
        float fn = valid ? f[c * NPIX + q] : 0.f;   // reference zero-pads f
        float d = fn - fc;
        s = fmaf(d, d, s);
    }
    kbuf[tap * NPIX + pix] = __expf(-0.5f * s);
}

// ---------------------------------------------------------------------------
// Kernel 2/3: one PAC layer.
//   out[o,p] = b[o] + sum_{tap,c} in[c, p+off(tap)] * k[tap,p] * W[o,c,tap]
// Block: 256 threads = 256 pixels; blockIdx.y picks 8 of 32 output channels.
// W slice for this output-group staged in LDS in 3 tap-chunks (27.6 KB).
// Wave-unanimous skip of taps whose k is numerically irrelevant (or fully OOB).
// FUSE variant recomputes k inline (fallback when ws is too small for kbuf).
// ---------------------------------------------------------------------------
template <bool FUSE>
__global__ __launch_bounds__(256) void pac_layer_kernel(
    const float* __restrict__ in, const float* __restrict__ f,
    const float* __restrict__ kbuf, const float* __restrict__ Wt,
    const float* __restrict__ bias, float* __restrict__ out)
{
    __shared__ float wl[NC * CHUNK * OPG];   // [(c*CHUNK+t)*OPG + o] : 27648 B
    const int og  = blockIdx.y;
    const int pix = blockIdx.x * 256 + threadIdx.x;
    const int h = pix >> 7, w = pix & (WW - 1);

    float acc[OPG];
#pragma unroll
    for (int i = 0; i < OPG; ++i) acc[i] = 0.f;

    float fc[NC];
    if (FUSE) {
#pragma unroll
        for (int c = 0; c < NC; ++c) fc[c] = f[c * NPIX + pix];
    }

    for (int ch = 0; ch < NCHUNK; ++ch) {
        __syncthreads();
        // Stage W chunk: source contiguous in tap (coalesced 27-runs).
        for (int idx = threadIdx.x; idx < NC * CHUNK * OPG; idx += 256) {
            int t = idx % CHUNK;
            int c = (idx / CHUNK) % NC;
            int o = idx / (CHUNK * NC);
            wl[(c * CHUNK + t) * OPG + o] =
                Wt[(og * OPG + o) * (NC * TAPS) + c * TAPS + ch * CHUNK + t];
        }
        __syncthreads();

        for (int t = 0; t < CHUNK; ++t) {
            int tap = ch * CHUNK + t;
            int qh = h + (tap / KS) * DIL - PAD;
            int qw = w + (tap % KS) * DIL - PAD;
            bool valid = ((unsigned)qh < HH) & ((unsigned)qw < WW);
            int q = qh * WW + qw;

            float kv;
            if (FUSE) {
                float s = 0.f;
#pragma unroll
                for (int c = 0; c < NC; ++c) {
                    float fn = valid ? f[c * NPIX + q] : 0.f;
                    float d = fn - fc[c];
                    s = fmaf(d, d, s);
                }
                kv = __expf(-0.5f * s);
            } else {
                kv = kbuf[tap * NPIX + pix];
            }

            // Skip tap if every lane's contribution is below numerical noise
            // (OOB taps contribute exactly 0 since x is zero-padded too).
            if (__all((kv < KMIN) | (!valid))) continue;

            const float* wp = &wl[t * OPG];
#pragma unroll 8
            for (int c = 0; c < NC; ++c) {
                float v = valid ? in[c * NPIX + q] : 0.f;
                v *= kv;
#pragma unroll
                for (int o = 0; o < OPG; ++o)
                    acc[o] = fmaf(v, wp[c * CHUNK * OPG + o], acc[o]);
            }
        }
    }

#pragma unroll
    for (int o = 0; o < OPG; ++o)
        out[(og * OPG + o) * NPIX + pix] = acc[o] + bias[og * OPG + o];
}

// ---------------------------------------------------------------------------
extern "C" void kernel_launch(void* const* d_in, const int* in_sizes, int n_in,
                              void* d_out, int out_size, void* d_ws, size_t ws_size,
                              hipStream_t stream)
{
    (void)in_sizes; (void)n_in; (void)out_size;
    const float* x  = (const float*)d_in[0];
    const float* f  = (const float*)d_in[1];
    const float* W1 = (const float*)d_in[2];
    const float* b1 = (const float*)d_in[3];
    const float* W2 = (const float*)d_in[4];
    const float* b2 = (const float*)d_in[5];
    float* out = (float*)d_out;

    const size_t kbytes = (size_t)TAPS * NPIX * sizeof(float);  // 5.3 MB
    const size_t hbytes = (size_t)NO * NPIX * sizeof(float);    // 2.0 MB
    const bool have_k = ws_size >= kbytes + hbytes;
    float* kbuf = have_k ? (float*)d_ws : nullptr;
    float* hbuf = have_k ? (float*)((char*)d_ws + kbytes) : (float*)d_ws;

    dim3 blk(256);
    dim3 grid(NPIX / 256, OG);   // 64 x 4 = 256 blocks = 1/CU
    if (have_k) {
        compute_k_kernel<<<dim3(TAPS * NPIX / 256), blk, 0, stream>>>(f, kbuf);
        pac_layer_kernel<false><<<grid, blk, 0, stream>>>(x,    f, kbuf, W1, b1, hbuf);
        pac_layer_kernel<false><<<grid, blk, 0, stream>>>(hbuf, f, kbuf, W2, b2, out);
    } else {
        pac_layer_kernel<true><<<grid, blk, 0, stream>>>(x,    f, nullptr, W1, b1, hbuf);
        pac_layer_kernel<true><<<grid, blk, 0, stream>>>(hbuf, f, nullptr, W2, b2, out);
    }
}